// Round 8
// baseline (445.691 us; speedup 1.0000x reference)
//
#include <hip/hip_runtime.h>
#include <hip/hip_bf16.h>
#include <hip/hip_cooperative_groups.h>
#include <cstdint>
#include <cstddef>

namespace cg = cooperative_groups;

// ---------------------------------------------------------------------------
// ResiduesNetwork: 2-layer GNN per protein + all-pairs MLP.
// pairs@fW0 = x1@fW0[:128] + x2@fW0[128:] (precompute A,B) => dominant cost
// is h0@fW1 per pair (21 GFLOP MFMA). Phase-1: split bf16 (hi+lo, 3 MFMA/
// k-step) for ~f32 accuracy, ALL fused into ONE cooperative kernel with
// grid.sync() between stages (phase-1 was ~78us across 9 tiny dependent
// graph nodes = mostly dispatch latency).
// Pair phase is FP16 end-to-end (R7: 58->~35us).
// HISTORY: launch_bounds min-waves forcing spilled breg twice (R3: 370MB,
// R6: VGPR 64 / 489MB scratch traffic). (256,2) here only caps VGPR at 256
// (need ~140) — safe; never cap below demand.
// ---------------------------------------------------------------------------

typedef __bf16 bf16_t;
typedef __bf16 bf16x8 __attribute__((ext_vector_type(8)));
typedef float f32x4 __attribute__((ext_vector_type(4)));
typedef _Float16 f16_t;
typedef _Float16 f16x8 __attribute__((ext_vector_type(8)));

static __device__ __forceinline__ f32x4 mfma_bf16(bf16x8 a, bf16x8 b, f32x4 c) {
  return __builtin_amdgcn_mfma_f32_16x16x32_bf16(a, b, c, 0, 0, 0);
}
static __device__ __forceinline__ f32x4 mfma_f16(f16x8 a, f16x8 b, f32x4 c) {
  return __builtin_amdgcn_mfma_f32_16x16x32_f16(a, b, c, 0, 0, 0);
}

#define N1R 800
#define NR  1600   // concat rows
#define VF  1024
#define F0  256    // conv0 out
#define F1  128    // conv1 out

// ---- split-bf16 GEMM body: C[M][N](+=) A[M][kslice] @ Bt[N][kslice]^T -----
// 256 thr = 4 waves, block tile 64x64, wave tile 32x32, 3 MFMA/k-step.
static __device__ void gemm_body(
    const bf16_t* __restrict__ Ah, const bf16_t* __restrict__ Al,
    const bf16_t* __restrict__ Bth, const bf16_t* __restrict__ Btl,
    const float* __restrict__ bias, float* __restrict__ C,
    f16_t* __restrict__ Ch,
    int M, int N, int K, int kStart, int kLen, int row0b, int col0b) {
  int lane = threadIdx.x & 63;
  int w = threadIdx.x >> 6;
  int wr = w >> 1, wc = w & 1;
  int jl = lane & 15, hi = lane >> 4;

  int row0 = row0b + wr * 32;
  int col0 = col0b + wc * 32;

  int r0 = min(row0 + jl, M - 1);
  int r1 = min(row0 + 16 + jl, M - 1);
  int c0 = col0 + jl;
  int c1 = col0 + 16 + jl;

  const bf16_t* pA0h = Ah + (size_t)r0 * K + hi * 8;
  const bf16_t* pA1h = Ah + (size_t)r1 * K + hi * 8;
  const bf16_t* pA0l = Al + (size_t)r0 * K + hi * 8;
  const bf16_t* pA1l = Al + (size_t)r1 * K + hi * 8;
  const bf16_t* pB0h = Bth + (size_t)c0 * K + hi * 8;
  const bf16_t* pB1h = Bth + (size_t)c1 * K + hi * 8;
  const bf16_t* pB0l = Btl + (size_t)c0 * K + hi * 8;
  const bf16_t* pB1l = Btl + (size_t)c1 * K + hi * 8;

  f32x4 acc[2][2] = {};
  for (int kb = kStart; kb < kStart + kLen; kb += 32) {
    bf16x8 a0h = *(const bf16x8*)(pA0h + kb);
    bf16x8 a1h = *(const bf16x8*)(pA1h + kb);
    bf16x8 a0l = *(const bf16x8*)(pA0l + kb);
    bf16x8 a1l = *(const bf16x8*)(pA1l + kb);
    bf16x8 b0h = *(const bf16x8*)(pB0h + kb);
    bf16x8 b1h = *(const bf16x8*)(pB1h + kb);
    bf16x8 b0l = *(const bf16x8*)(pB0l + kb);
    bf16x8 b1l = *(const bf16x8*)(pB1l + kb);

    acc[0][0] = mfma_bf16(a0h, b0h, acc[0][0]);
    acc[0][1] = mfma_bf16(a0h, b1h, acc[0][1]);
    acc[1][0] = mfma_bf16(a1h, b0h, acc[1][0]);
    acc[1][1] = mfma_bf16(a1h, b1h, acc[1][1]);

    acc[0][0] = mfma_bf16(a0l, b0h, acc[0][0]);
    acc[0][1] = mfma_bf16(a0l, b1h, acc[0][1]);
    acc[1][0] = mfma_bf16(a1l, b0h, acc[1][0]);
    acc[1][1] = mfma_bf16(a1l, b1h, acc[1][1]);

    acc[0][0] = mfma_bf16(a0h, b0l, acc[0][0]);
    acc[0][1] = mfma_bf16(a0h, b1l, acc[0][1]);
    acc[1][0] = mfma_bf16(a1h, b0l, acc[1][0]);
    acc[1][1] = mfma_bf16(a1h, b1l, acc[1][1]);
  }

  #pragma unroll
  for (int m = 0; m < 2; ++m) {
    #pragma unroll
    for (int nn = 0; nn < 2; ++nn) {
      int col = col0 + nn * 16 + jl;
      float bv = bias ? bias[col] : 0.f;
      #pragma unroll
      for (int reg = 0; reg < 4; ++reg) {
        int row = row0 + m * 16 + hi * 4 + reg;
        if (row < M) {
          float val = acc[m][nn][reg] + bv;
          if (Ch) Ch[(size_t)row * N + col] = (f16_t)val;
          else    C[(size_t)row * N + col] = val;
        }
      }
    }
  }
}

// ---- cooperative phase-1 mega-kernel --------------------------------------
struct P1Args {
  const float *Z1, *Z2, *Wr0, *Wnr0, *Wr1, *Wnr1, *fW0, *fb0, *fW1, *fb1, *fW2, *fb2;
  const int *nb1, *nb2;
  bf16_t *Zh, *Zl, *W0h, *W0l, *W1h, *W1l, *fAh, *fAl, *fBh, *fBl;
  f16_t *fW1th;
  float *fbw;
  float *RB0p, *RB1p;    // split-K4 partials
  bf16_t *H0h, *H0l, *H1h, *H1l;
  f16_t *ABh;
};

__global__ __launch_bounds__(256, 2) void phase1_kernel(P1Args a) {
  cg::grid_group grid = cg::this_grid();
  const int nb = gridDim.x;
  const int tid = threadIdx.x;

  // ---- P0: conversions (Z hi/lo x4-vectorized; weights transposed; fbw) ---
  for (int bx = blockIdx.x; bx < 4225; bx += nb) {
    if (bx < 1600) {
      int t4 = (bx * 256 + tid) * 4;
      int r = t4 >> 10;
      int c = t4 & (VF - 1);
      float4 v = (r < N1R) ? *(const float4*)(a.Z1 + r * VF + c)
                           : *(const float4*)(a.Z2 + (r - N1R) * VF + c);
      float vv[4] = {v.x, v.y, v.z, v.w};
      #pragma unroll
      for (int u = 0; u < 4; ++u) {
        bf16_t h = (bf16_t)vv[u];
        a.Zh[t4 + u] = h;
        a.Zl[t4 + u] = (bf16_t)(vv[u] - (float)h);
      }
      continue;
    }
    int wb = bx - 1600;
    if (wb >= 2560 && wb < 2624) {  // fW1 [256][64] -> f16 transposed [64][256]
      int t = (wb - 2560) * 256 + tid;
      int n = t & 63;
      int k = t >> 6;
      a.fW1th[(n << 8) + k] = (f16_t)a.fW1[k * 64 + n];
      continue;
    }
    if (wb == 2624) {  // epilogue-constant table
      if (tid < 128) {
        int jl = tid & 15, s = tid >> 4;
        a.fbw[jl * 8 + s] = (s < 4) ? a.fb1[s * 16 + jl] : a.fW2[(s - 4) * 16 + jl];
      } else if (tid == 128) {
        a.fbw[128] = a.fb2[0];
      }
      continue;
    }
    const float* src; bf16_t* dh; bf16_t* dl; int ld, lk, ln, b0;
    if      (wb < 1024) { src = a.Wr0;  ld = 256; lk = 10; ln = 8; dh = a.W0h;              dl = a.W0l;              b0 = 0;    }
    else if (wb < 2048) { src = a.Wnr0; ld = 256; lk = 10; ln = 8; dh = a.W0h + 256 * 1024; dl = a.W0l + 256 * 1024; b0 = 1024; }
    else if (wb < 2176) { src = a.Wr1;  ld = 128; lk = 8;  ln = 7; dh = a.W1h;              dl = a.W1l;              b0 = 2048; }
    else if (wb < 2304) { src = a.Wnr1; ld = 128; lk = 8;  ln = 7; dh = a.W1h + 128 * 256;  dl = a.W1l + 128 * 256;  b0 = 2176; }
    else if (wb < 2432) { src = a.fW0;             ld = 256; lk = 7; ln = 8; dh = a.fAh;    dl = a.fAl;              b0 = 2304; }
    else                { src = a.fW0 + 128 * 256; ld = 256; lk = 7; ln = 8; dh = a.fBh;    dl = a.fBl;              b0 = 2432; }
    int t = (wb - b0) * 256 + tid;
    int n = t & ((1 << ln) - 1);
    int k = t >> ln;
    float v = src[k * ld + n];
    bf16_t h = (bf16_t)v;
    dh[(n << lk) + k] = h;
    dl[(n << lk) + k] = (bf16_t)(v - (float)h);
  }
  grid.sync();

  // ---- P1: gemm1 split-K4: RB0p[z][1600][512] = Z @ [Wr0|Wnr0], 800 jobs --
  for (int job = blockIdx.x; job < 800; job += nb) {
    int z = job & 3, tile = job >> 2;                  // tile: 25y x 8x
    gemm_body(a.Zh, a.Zl, a.W0h, a.W0l, nullptr,
              a.RB0p + (size_t)z * NR * 512, nullptr,
              NR, 512, 1024, z * 256, 256, (tile >> 3) * 64, (tile & 7) * 64);
  }
  grid.sync();

  // ---- P2: agg1 (sums 4 partials inline) -> H0 hi/lo ----------------------
  for (int row = blockIdx.x; row < NR; row += nb) {
    int c = tid;  // 0..255
    const int* nbp; int roff;
    if (row < N1R) { nbp = a.nb1 + row * 10; roff = 0; }
    else           { nbp = a.nb2 + (row - N1R) * 10; roff = N1R; }
    const size_t P = (size_t)NR * 512;
    float s = 0.f; int cnt = 0;
    #pragma unroll
    for (int k = 0; k < 10; ++k) {
      int idx = nbp[k];
      if (idx > -1) {
        cnt++;
        size_t o = (size_t)(roff + idx) * 512 + 256 + c;
        s += a.RB0p[o] + a.RB0p[o + P] + a.RB0p[o + 2 * P] + a.RB0p[o + 3 * P];
      }
    }
    size_t so = (size_t)row * 512 + c;
    float v = a.RB0p[so] + a.RB0p[so + P] + a.RB0p[so + 2 * P] + a.RB0p[so + 3 * P];
    v += s / (float)(cnt > 0 ? cnt : 1);
    v = fmaxf(v, 0.f);
    bf16_t h = (bf16_t)v;
    a.H0h[(size_t)row * F0 + c] = h;
    a.H0l[(size_t)row * F0 + c] = (bf16_t)(v - (float)h);
  }
  grid.sync();

  // ---- P3: gemm2 split-K4: RB1p[z][1600][256] = H0 @ [Wr1|Wnr1], 400 jobs -
  for (int job = blockIdx.x; job < 400; job += nb) {
    int z = job & 3, tile = job >> 2;                  // tile: 25y x 4x
    gemm_body(a.H0h, a.H0l, a.W1h, a.W1l, nullptr,
              a.RB1p + (size_t)z * NR * 256, nullptr,
              NR, 256, 256, z * 64, 64, (tile >> 2) * 64, (tile & 3) * 64);
  }
  grid.sync();

  // ---- P4: agg2 (sums 4 partials inline) -> H1 hi/lo ----------------------
  for (int row = blockIdx.x; row < NR; row += nb) {
    int c = tid;
    if (c < F1) {
      const int* nbp; int roff;
      if (row < N1R) { nbp = a.nb1 + row * 10; roff = 0; }
      else           { nbp = a.nb2 + (row - N1R) * 10; roff = N1R; }
      const size_t P = (size_t)NR * 256;
      float s = 0.f; int cnt = 0;
      #pragma unroll
      for (int k = 0; k < 10; ++k) {
        int idx = nbp[k];
        if (idx > -1) {
          cnt++;
          size_t o = (size_t)(roff + idx) * 256 + 128 + c;
          s += a.RB1p[o] + a.RB1p[o + P] + a.RB1p[o + 2 * P] + a.RB1p[o + 3 * P];
        }
      }
      size_t so = (size_t)row * 256 + c;
      float v = a.RB1p[so] + a.RB1p[so + P] + a.RB1p[so + 2 * P] + a.RB1p[so + 3 * P];
      v += s / (float)(cnt > 0 ? cnt : 1);
      v = fmaxf(v, 0.f);
      bf16_t h = (bf16_t)v;
      a.H1h[(size_t)row * F1 + c] = h;
      a.H1l[(size_t)row * F1 + c] = (bf16_t)(v - (float)h);
    }
  }
  grid.sync();

  // ---- P5: dual GEMM -> ABh f16 (A' = x1@fW0top + fb0 ; B = x2@fW0bot) ----
  for (int job = blockIdx.x; job < 104; job += nb) {
    int part = (job >= 52) ? 1 : 0;
    int rem = job - part * 52;                         // 13 my x 4 bx
    gemm_body(a.H1h + (size_t)part * N1R * F1, a.H1l + (size_t)part * N1R * F1,
              part ? a.fBh : a.fAh, part ? a.fBl : a.fAl, part ? nullptr : a.fb0,
              nullptr, a.ABh + (size_t)part * N1R * 256, N1R, 256, F1, 0, F1,
              (rem >> 2) * 64, (rem & 3) * 64);
  }
}

// ---- pair kernel (FP16): out[i,j] = fb2 + relu(relu(A'[i]+B[j])@fW1+fb1).fW2
// block: 64 j (4 waves x 16) x 16 i.  B rows in regs (f16x8 x8 = 32 VGPR),
// A' broadcast from LDS (f16), fW1t f16 in LDS (XOR-swizzled).
// LDS = 32KB W + 8KB A = 40960B exactly => 4 blocks/CU cap.
#define IBLK 2
#define ITILE 16
__global__ __launch_bounds__(256) void pair_kernel(
    const f16_t* __restrict__ ABh, const f16_t* __restrict__ W1th,
    const float* __restrict__ fbw, float* __restrict__ out) {
  __shared__ alignas(16) unsigned char sWh[64 * 512];   // [n][512B] swizzled
  __shared__ alignas(16) f16_t sA[ITILE * 256];         // 8KB

  const int tid = threadIdx.x;
  const int lane = tid & 63;
  const int w = tid >> 6;
  const int jl = lane & 15;
  const int hi = lane >> 4;
  const int j0 = blockIdx.x * 64;
  const int i0 = blockIdx.y * ITILE;

  // stage fW1t f16 [64][256] -> LDS, swizzle byte^=((n&7)<<4) in-row
  #pragma unroll
  for (int s = 0; s < 8; ++s) {
    int c = tid + 256 * s;
    int n = c >> 5;
    int cb = (c & 31) << 4;
    int sw = cb ^ ((n & 7) << 4);
    *(uint4*)(sWh + n * 512 + sw) = *(const uint4*)((const unsigned char*)W1th + n * 512 + cb);
  }
  // stage A' rows i0..i0+15 (f16): 512 x 16B chunks, 32 per row
  #pragma unroll
  for (int s = 0; s < 2; ++s) {
    int c = tid + 256 * s;
    int rr = c >> 5;
    int cc = c & 31;
    *(uint4*)((unsigned char*)sA + rr * 512 + cc * 16) =
        *(const uint4*)(ABh + (size_t)(i0 + rr) * 256 + cc * 8);
  }

  // B row of this lane's pair -> registers (its k-slice: 64 f16 = 32 VGPR)
  int j = j0 + w * 16 + jl;
  f16x8 breg[8];
  {
    const f16_t* Bp = ABh + (size_t)(N1R + j) * 256;
    bool ok = (j < N1R);
    f16x8 z{};
    #pragma unroll
    for (int t = 0; t < 8; ++t)
      breg[t] = ok ? *(const f16x8*)(Bp + t * 32 + hi * 8) : z;
  }

  // epilogue constants: 2 vector loads from pre-transposed table
  float4 fb1r = *(const float4*)(fbw + jl * 8);
  float4 fw2r = *(const float4*)(fbw + jl * 8 + 4);
  float bias2 = fbw[128];

  __syncthreads();

  #pragma unroll 1
  for (int ig = 0; ig < ITILE / IBLK; ++ig) {
    f32x4 acc[IBLK][4] = {};
    #pragma unroll
    for (int t = 0; t < 8; ++t) {
      f16x8 bv = breg[t];
      f16x8 af[IBLK];
      const f16x8 Zv{};
      #pragma unroll
      for (int ib = 0; ib < IBLK; ++ib) {
        f16x8 av = *(const f16x8*)(sA + (ig * IBLK + ib) * 256 + t * 32 + hi * 8);
        af[ib] = __builtin_elementwise_max(av + bv, Zv);  // pk_add + pk_max
      }
      int kbyte = t * 64 + hi * 16;
      #pragma unroll
      for (int nf = 0; nf < 4; ++nf) {
        int n = nf * 16 + jl;
        f16x8 wh = *(const f16x8*)(sWh + n * 512 + (kbyte ^ ((n & 7) << 4)));
        #pragma unroll
        for (int ib = 0; ib < IBLK; ++ib)
          acc[ib][nf] = mfma_f16(af[ib], wh, acc[ib][nf]);
      }
    }
    // epilogue: h1 = relu(acc + fb1); out = h1 . fW2 + fb2
    float fb1a[4] = {fb1r.x, fb1r.y, fb1r.z, fb1r.w};
    float fw2a[4] = {fw2r.x, fw2r.y, fw2r.z, fw2r.w};
    #pragma unroll
    for (int ib = 0; ib < IBLK; ++ib) {
      float part[4];
      #pragma unroll
      for (int r = 0; r < 4; ++r) {
        float ssum = 0.f;
        #pragma unroll
        for (int nf = 0; nf < 4; ++nf) {
          float h = acc[ib][nf][r] + fb1a[nf];
          h = fmaxf(h, 0.f);
          ssum += h * fw2a[nf];
        }
        part[r] = ssum;
      }
      #pragma unroll
      for (int off = 1; off < 16; off <<= 1) {
        #pragma unroll
        for (int r = 0; r < 4; ++r) part[r] += __shfl_xor(part[r], off, 64);
      }
      if (jl == 0) {
        int jo = j0 + w * 16 + hi * 4;
        if (jo < N1R) {
          float4 o = make_float4(part[0] + bias2, part[1] + bias2,
                                 part[2] + bias2, part[3] + bias2);
          *(float4*)(out + (size_t)(i0 + ig * IBLK + ib) * 800 + jo) = o;
        }
      }
    }
  }
}

// ---------------------------------------------------------------------------
extern "C" void kernel_launch(void* const* d_in, const int* in_sizes, int n_in,
                              void* d_out, int out_size, void* d_ws, size_t ws_size,
                              hipStream_t stream) {
  P1Args a;
  a.Z1   = (const float*)d_in[0];
  a.nb1  = (const int*)d_in[1];
  a.Z2   = (const float*)d_in[2];
  a.nb2  = (const int*)d_in[3];
  a.Wr0  = (const float*)d_in[4];
  a.Wnr0 = (const float*)d_in[5];
  a.Wr1  = (const float*)d_in[6];
  a.Wnr1 = (const float*)d_in[7];
  a.fW0  = (const float*)d_in[8];
  a.fb0  = (const float*)d_in[9];
  a.fW1  = (const float*)d_in[10];
  a.fb1  = (const float*)d_in[11];
  a.fW2  = (const float*)d_in[12];
  a.fb2  = (const float*)d_in[13];
  float* out = (float*)d_out;

  // workspace carve
  char* p = (char*)d_ws;
  auto alloc = [&](size_t bytes) {
    char* q = p;
    p += (bytes + 255) & ~(size_t)255;
    return q;
  };
  a.Zh    = (bf16_t*)alloc((size_t)NR * VF * 2);
  a.Zl    = (bf16_t*)alloc((size_t)NR * VF * 2);
  a.W0h   = (bf16_t*)alloc((size_t)512 * 1024 * 2);
  a.W0l   = (bf16_t*)alloc((size_t)512 * 1024 * 2);
  a.W1h   = (bf16_t*)alloc((size_t)256 * 256 * 2);
  a.W1l   = (bf16_t*)alloc((size_t)256 * 256 * 2);
  a.fAh   = (bf16_t*)alloc((size_t)256 * 128 * 2);
  a.fAl   = (bf16_t*)alloc((size_t)256 * 128 * 2);
  a.fBh   = (bf16_t*)alloc((size_t)256 * 128 * 2);
  a.fBl   = (bf16_t*)alloc((size_t)256 * 128 * 2);
  a.fW1th = (f16_t*)alloc((size_t)64 * 256 * 2);
  a.fbw   = (float*)alloc(129 * 4);
  a.RB0p  = (float*)alloc((size_t)4 * NR * 512 * 4);
  a.RB1p  = (float*)alloc((size_t)4 * NR * 256 * 4);
  a.H0h   = (bf16_t*)alloc((size_t)NR * F0 * 2);
  a.H0l   = (bf16_t*)alloc((size_t)NR * F0 * 2);
  a.H1h   = (bf16_t*)alloc((size_t)NR * F1 * 2);
  a.H1l   = (bf16_t*)alloc((size_t)NR * F1 * 2);
  a.ABh   = (f16_t*)alloc((size_t)NR * 256 * 2);
  (void)in_sizes; (void)n_in; (void)out_size; (void)ws_size;

  // 1. entire phase-1 as one cooperative kernel (512 blocks, 2/CU guaranteed)
  P1Args ha = a;
  void* kargs[] = { &ha };
  hipLaunchCooperativeKernel((void*)phase1_kernel, dim3(512), dim3(256),
                             kargs, 0, stream);
  // 2. all-pairs fused MLP (fp16 datapath)
  pair_kernel<<<dim3(13, 50), 256, 0, stream>>>(a.ABh, a.fW1th, a.fbw, out);
}

// Round 9
// 119.527 us; speedup vs baseline: 3.7288x; 3.7288x over previous
//
#include <hip/hip_runtime.h>
#include <hip/hip_bf16.h>
#include <cstdint>
#include <cstddef>

// ---------------------------------------------------------------------------
// ResiduesNetwork: 2-layer GNN per protein + all-pairs MLP.
// pairs@fW0 = x1@fW0[:128] + x2@fW0[128:] (precompute A,B) => dominant cost
// is h0@fW1 per pair (21 GFLOP MFMA). Phase-1: split bf16 (hi+lo, 3 MFMA/
// k-step) ~f32 accuracy; gemm1 converts A from f32 Z on the fly.
// Pair phase FP16 end-to-end (R7-proven).
// HISTORY: (a) launch_bounds min-waves forcing spilled breg (R3/R6: 370/489MB
// scratch traffic) — never cap VGPR below demand. (b) cooperative mega-kernel
// fusion (R8) ran 404us: 512-block co-residency strangles latency hiding and
// grid.sync spins across XCDs — keep the multi-kernel graph.
// ---------------------------------------------------------------------------

typedef __bf16 bf16_t;
typedef __bf16 bf16x8 __attribute__((ext_vector_type(8)));
typedef float f32x4 __attribute__((ext_vector_type(4)));
typedef _Float16 f16_t;
typedef _Float16 f16x8 __attribute__((ext_vector_type(8)));

static __device__ __forceinline__ f32x4 mfma_bf16(bf16x8 a, bf16x8 b, f32x4 c) {
  return __builtin_amdgcn_mfma_f32_16x16x32_bf16(a, b, c, 0, 0, 0);
}
static __device__ __forceinline__ f32x4 mfma_f16(f16x8 a, f16x8 b, f32x4 c) {
  return __builtin_amdgcn_mfma_f32_16x16x32_f16(a, b, c, 0, 0, 0);
}

#define N1R 800
#define NR  1600   // concat rows
#define VF  1024
#define F0  256    // conv0 out
#define F1  128    // conv1 out

// ---- weight conversion/transpose + epilogue table (2625 blocks) ------------
__global__ void conv_w(const float* __restrict__ Wr0, const float* __restrict__ Wnr0,
                       const float* __restrict__ Wr1, const float* __restrict__ Wnr1,
                       const float* __restrict__ fW0, const float* __restrict__ fW1,
                       const float* __restrict__ fb1, const float* __restrict__ fW2,
                       const float* __restrict__ fb2,
                       bf16_t* __restrict__ W0h, bf16_t* __restrict__ W0l,
                       bf16_t* __restrict__ W1h, bf16_t* __restrict__ W1l,
                       bf16_t* __restrict__ fAh, bf16_t* __restrict__ fAl,
                       bf16_t* __restrict__ fBh, bf16_t* __restrict__ fBl,
                       f16_t* __restrict__ fW1th, float* __restrict__ fbw) {
  int wb = blockIdx.x;
  if (wb >= 2560 && wb < 2624) {  // fW1 [256][64] -> f16 transposed [64][256]
    int t = (wb - 2560) * 256 + threadIdx.x;
    int n = t & 63;
    int k = t >> 6;
    fW1th[(n << 8) + k] = (f16_t)fW1[k * 64 + n];
    return;
  }
  if (wb == 2624) {  // epilogue-constant table: fbw[jl*8+s]=fb1/fW2 slices
    int t = threadIdx.x;
    if (t < 128) {
      int jl = t & 15, s = t >> 4;
      fbw[jl * 8 + s] = (s < 4) ? fb1[s * 16 + jl] : fW2[(s - 4) * 16 + jl];
    } else if (t == 128) {
      fbw[128] = fb2[0];
    }
    return;
  }
  const float* src; bf16_t* dh; bf16_t* dl; int ld, lk, ln, b0;
  if      (wb < 1024) { src = Wr0;  ld = 256; lk = 10; ln = 8; dh = W0h;              dl = W0l;              b0 = 0;    }
  else if (wb < 2048) { src = Wnr0; ld = 256; lk = 10; ln = 8; dh = W0h + 256 * 1024; dl = W0l + 256 * 1024; b0 = 1024; }
  else if (wb < 2176) { src = Wr1;  ld = 128; lk = 8;  ln = 7; dh = W1h;              dl = W1l;              b0 = 2048; }
  else if (wb < 2304) { src = Wnr1; ld = 128; lk = 8;  ln = 7; dh = W1h + 128 * 256;  dl = W1l + 128 * 256;  b0 = 2176; }
  else if (wb < 2432) { src = fW0;             ld = 256; lk = 7; ln = 8; dh = fAh;    dl = fAl;              b0 = 2304; }
  else                { src = fW0 + 128 * 256; ld = 256; lk = 7; ln = 8; dh = fBh;    dl = fBl;              b0 = 2432; }
  int t = (wb - b0) * 256 + threadIdx.x;
  int n = t & ((1 << ln) - 1);
  int k = t >> ln;
  float v = src[k * ld + n];
  bf16_t h = (bf16_t)v;
  dh[(n << lk) + k] = h;
  dl[(n << lk) + k] = (bf16_t)(v - (float)h);
}

// split f32 -> (hi bf16x8, lo bf16x8) from two float4
static __device__ __forceinline__ void split8(float4 va, float4 vb,
                                              bf16x8& h8, bf16x8& l8) {
  float v[8] = {va.x, va.y, va.z, va.w, vb.x, vb.y, vb.z, vb.w};
  #pragma unroll
  for (int e = 0; e < 8; ++e) {
    bf16_t h = (bf16_t)v[e];
    h8[e] = h;
    l8[e] = (bf16_t)(v[e] - (float)h);
  }
}

// ---- gemm1 (split-K): RB0p[z] = Z(f32, on-the-fly split) @ W0^T ------------
// grid (8, 25, S), 256 thr; tile 64x64; K=1024, kLen=1024/S.
__global__ __launch_bounds__(256) void gemm_z(
    const float* __restrict__ Z1, const float* __restrict__ Z2,
    const bf16_t* __restrict__ Bth, const bf16_t* __restrict__ Btl,
    float* __restrict__ Cp, int kLen) {
  int lane = threadIdx.x & 63;
  int w = threadIdx.x >> 6;
  int wr = w >> 1, wc = w & 1;
  int jl = lane & 15, hi = lane >> 4;

  int row0 = blockIdx.y * 64 + wr * 32;
  int col0 = blockIdx.x * 64 + wc * 32;
  int z = blockIdx.z;
  int kStart = z * kLen;
  float* C = Cp + (size_t)z * NR * 512;

  int r0 = row0 + jl;
  int r1 = row0 + 16 + jl;
  int c0 = col0 + jl;
  int c1 = col0 + 16 + jl;

  const float* pZ0 = ((r0 < N1R) ? Z1 + (size_t)r0 * VF : Z2 + (size_t)(r0 - N1R) * VF) + hi * 8;
  const float* pZ1 = ((r1 < N1R) ? Z1 + (size_t)r1 * VF : Z2 + (size_t)(r1 - N1R) * VF) + hi * 8;
  const bf16_t* pB0h = Bth + (size_t)c0 * 1024 + hi * 8;
  const bf16_t* pB1h = Bth + (size_t)c1 * 1024 + hi * 8;
  const bf16_t* pB0l = Btl + (size_t)c0 * 1024 + hi * 8;
  const bf16_t* pB1l = Btl + (size_t)c1 * 1024 + hi * 8;

  f32x4 acc[2][2] = {};
  for (int kb = kStart; kb < kStart + kLen; kb += 32) {
    bf16x8 a0h, a0l, a1h, a1l;
    split8(*(const float4*)(pZ0 + kb), *(const float4*)(pZ0 + kb + 4), a0h, a0l);
    split8(*(const float4*)(pZ1 + kb), *(const float4*)(pZ1 + kb + 4), a1h, a1l);
    bf16x8 b0h = *(const bf16x8*)(pB0h + kb);
    bf16x8 b1h = *(const bf16x8*)(pB1h + kb);
    bf16x8 b0l = *(const bf16x8*)(pB0l + kb);
    bf16x8 b1l = *(const bf16x8*)(pB1l + kb);

    acc[0][0] = mfma_bf16(a0h, b0h, acc[0][0]);
    acc[0][1] = mfma_bf16(a0h, b1h, acc[0][1]);
    acc[1][0] = mfma_bf16(a1h, b0h, acc[1][0]);
    acc[1][1] = mfma_bf16(a1h, b1h, acc[1][1]);

    acc[0][0] = mfma_bf16(a0l, b0h, acc[0][0]);
    acc[0][1] = mfma_bf16(a0l, b1h, acc[0][1]);
    acc[1][0] = mfma_bf16(a1l, b0h, acc[1][0]);
    acc[1][1] = mfma_bf16(a1l, b1h, acc[1][1]);

    acc[0][0] = mfma_bf16(a0h, b0l, acc[0][0]);
    acc[0][1] = mfma_bf16(a0h, b1l, acc[0][1]);
    acc[1][0] = mfma_bf16(a1h, b0l, acc[1][0]);
    acc[1][1] = mfma_bf16(a1h, b1l, acc[1][1]);
  }

  #pragma unroll
  for (int m = 0; m < 2; ++m) {
    #pragma unroll
    for (int nn = 0; nn < 2; ++nn) {
      int col = col0 + nn * 16 + jl;
      #pragma unroll
      for (int reg = 0; reg < 4; ++reg) {
        int row = row0 + m * 16 + hi * 4 + reg;
        C[(size_t)row * 512 + col] = acc[m][nn][reg];
      }
    }
  }
}

// ---- generic split-bf16 GEMM body (bf16 A from memory) ---------------------
static __device__ __forceinline__ void gemm_body(
    const bf16_t* __restrict__ Ah, const bf16_t* __restrict__ Al,
    const bf16_t* __restrict__ Bth, const bf16_t* __restrict__ Btl,
    const float* __restrict__ bias, float* __restrict__ C,
    f16_t* __restrict__ Ch,
    int M, int N, int K, int kStart, int kLen, int row0b, int col0b) {
  int lane = threadIdx.x & 63;
  int w = threadIdx.x >> 6;
  int wr = w >> 1, wc = w & 1;
  int jl = lane & 15, hi = lane >> 4;

  int row0 = row0b + wr * 32;
  int col0 = col0b + wc * 32;

  int r0 = min(row0 + jl, M - 1);
  int r1 = min(row0 + 16 + jl, M - 1);
  int c0 = col0 + jl;
  int c1 = col0 + 16 + jl;

  const bf16_t* pA0h = Ah + (size_t)r0 * K + hi * 8;
  const bf16_t* pA1h = Ah + (size_t)r1 * K + hi * 8;
  const bf16_t* pA0l = Al + (size_t)r0 * K + hi * 8;
  const bf16_t* pA1l = Al + (size_t)r1 * K + hi * 8;
  const bf16_t* pB0h = Bth + (size_t)c0 * K + hi * 8;
  const bf16_t* pB1h = Bth + (size_t)c1 * K + hi * 8;
  const bf16_t* pB0l = Btl + (size_t)c0 * K + hi * 8;
  const bf16_t* pB1l = Btl + (size_t)c1 * K + hi * 8;

  f32x4 acc[2][2] = {};
  for (int kb = kStart; kb < kStart + kLen; kb += 32) {
    bf16x8 a0h = *(const bf16x8*)(pA0h + kb);
    bf16x8 a1h = *(const bf16x8*)(pA1h + kb);
    bf16x8 a0l = *(const bf16x8*)(pA0l + kb);
    bf16x8 a1l = *(const bf16x8*)(pA1l + kb);
    bf16x8 b0h = *(const bf16x8*)(pB0h + kb);
    bf16x8 b1h = *(const bf16x8*)(pB1h + kb);
    bf16x8 b0l = *(const bf16x8*)(pB0l + kb);
    bf16x8 b1l = *(const bf16x8*)(pB1l + kb);

    acc[0][0] = mfma_bf16(a0h, b0h, acc[0][0]);
    acc[0][1] = mfma_bf16(a0h, b1h, acc[0][1]);
    acc[1][0] = mfma_bf16(a1h, b0h, acc[1][0]);
    acc[1][1] = mfma_bf16(a1h, b1h, acc[1][1]);

    acc[0][0] = mfma_bf16(a0l, b0h, acc[0][0]);
    acc[0][1] = mfma_bf16(a0l, b1h, acc[0][1]);
    acc[1][0] = mfma_bf16(a1l, b0h, acc[1][0]);
    acc[1][1] = mfma_bf16(a1l, b1h, acc[1][1]);

    acc[0][0] = mfma_bf16(a0h, b0l, acc[0][0]);
    acc[0][1] = mfma_bf16(a0h, b1l, acc[0][1]);
    acc[1][0] = mfma_bf16(a1h, b0l, acc[1][0]);
    acc[1][1] = mfma_bf16(a1h, b1l, acc[1][1]);
  }

  #pragma unroll
  for (int m = 0; m < 2; ++m) {
    #pragma unroll
    for (int nn = 0; nn < 2; ++nn) {
      int col = col0 + nn * 16 + jl;
      float bv = bias ? bias[col] : 0.f;
      #pragma unroll
      for (int reg = 0; reg < 4; ++reg) {
        int row = row0 + m * 16 + hi * 4 + reg;
        if (row < M) {
          float val = acc[m][nn][reg] + bv;
          if (Ch) Ch[(size_t)row * N + col] = (f16_t)val;
          else    C[(size_t)row * N + col] = val;
        }
      }
    }
  }
}

// gemm2 split-K: RB1p[z] = H0 @ [Wr1|Wnr1] slice
__global__ __launch_bounds__(256) void gemm_split(
    const bf16_t* __restrict__ Ah, const bf16_t* __restrict__ Al,
    const bf16_t* __restrict__ Bth, const bf16_t* __restrict__ Btl,
    float* __restrict__ Cp, int M, int N, int K, int kLen) {
  int z = blockIdx.z;
  gemm_body(Ah, Al, Bth, Btl, nullptr, Cp + (size_t)z * M * N, nullptr,
            M, N, K, z * kLen, kLen, blockIdx.y * 64, blockIdx.x * 64);
}

// dual GEMM -> f16: A' = x1@fW0top + fb0 ; B = x2@fW0bot (one launch).
__global__ __launch_bounds__(256) void gemm_dual(
    const bf16_t* __restrict__ H1h, const bf16_t* __restrict__ H1l,
    const bf16_t* __restrict__ fAh, const bf16_t* __restrict__ fAl,
    const bf16_t* __restrict__ fBh, const bf16_t* __restrict__ fBl,
    const float* __restrict__ fb0, f16_t* __restrict__ ABh) {
  int part = blockIdx.y / 13;
  int my = blockIdx.y % 13;
  gemm_body(H1h + (size_t)part * N1R * F1, H1l + (size_t)part * N1R * F1,
            part ? fBh : fAh, part ? fBl : fAl, part ? nullptr : fb0,
            nullptr, ABh + (size_t)part * N1R * 256, N1R, 256, F1, 0, F1,
            my * 64, blockIdx.x * 64);
}

// ---- GNN aggregate with inline split-K partial sum -------------------------
// RBp: [S][1600][2F]; H = relu(sum_z res + gather-sum(sum_z base)/norm)
__global__ void agg_kernel(const float* __restrict__ RBp, const int* __restrict__ nb1,
                           const int* __restrict__ nb2, bf16_t* __restrict__ Hh,
                           bf16_t* __restrict__ Hl, int F, int S) {
  int row = blockIdx.x;
  int c = threadIdx.x;
  int Sw = 2 * F;
  const size_t P = (size_t)NR * Sw;
  const int* nb;
  int roff;
  if (row < N1R) { nb = nb1 + row * 10; roff = 0; }
  else           { nb = nb2 + (row - N1R) * 10; roff = N1R; }
  float s = 0.f; int cnt = 0;
  #pragma unroll
  for (int k = 0; k < 10; ++k) {
    int idx = nb[k];
    if (idx > -1) {
      cnt++;
      size_t o = (size_t)(roff + idx) * Sw + F + c;
      float t = 0.f;
      for (int z = 0; z < S; ++z) t += RBp[o + (size_t)z * P];
      s += t;
    }
  }
  size_t so = (size_t)row * Sw + c;
  float v = 0.f;
  for (int z = 0; z < S; ++z) v += RBp[so + (size_t)z * P];
  v += s / (float)(cnt > 0 ? cnt : 1);
  v = fmaxf(v, 0.f);
  bf16_t h = (bf16_t)v;
  Hh[(size_t)row * F + c] = h;
  Hl[(size_t)row * F + c] = (bf16_t)(v - (float)h);
}

// ---- pair kernel (FP16, R7-proven): out = fb2 + relu(relu(A'+B)@fW1+fb1).fW2
#define IBLK 2
#define ITILE 16
__global__ __launch_bounds__(256) void pair_kernel(
    const f16_t* __restrict__ ABh, const f16_t* __restrict__ W1th,
    const float* __restrict__ fbw, float* __restrict__ out) {
  __shared__ alignas(16) unsigned char sWh[64 * 512];   // [n][512B] swizzled
  __shared__ alignas(16) f16_t sA[ITILE * 256];         // 8KB

  const int tid = threadIdx.x;
  const int lane = tid & 63;
  const int w = tid >> 6;
  const int jl = lane & 15;
  const int hi = lane >> 4;
  const int j0 = blockIdx.x * 64;
  const int i0 = blockIdx.y * ITILE;

  // stage fW1t f16 [64][256] -> LDS, swizzle byte^=((n&7)<<4) in-row
  #pragma unroll
  for (int s = 0; s < 8; ++s) {
    int c = tid + 256 * s;
    int n = c >> 5;
    int cb = (c & 31) << 4;
    int sw = cb ^ ((n & 7) << 4);
    *(uint4*)(sWh + n * 512 + sw) = *(const uint4*)((const unsigned char*)W1th + n * 512 + cb);
  }
  // stage A' rows i0..i0+15 (f16): 512 x 16B chunks, 32 per row
  #pragma unroll
  for (int s = 0; s < 2; ++s) {
    int c = tid + 256 * s;
    int rr = c >> 5;
    int cc = c & 31;
    *(uint4*)((unsigned char*)sA + rr * 512 + cc * 16) =
        *(const uint4*)(ABh + (size_t)(i0 + rr) * 256 + cc * 8);
  }

  // B row of this lane's pair -> registers (its k-slice: 64 f16 = 32 VGPR)
  int j = j0 + w * 16 + jl;
  f16x8 breg[8];
  {
    const f16_t* Bp = ABh + (size_t)(N1R + j) * 256;
    bool ok = (j < N1R);
    f16x8 z{};
    #pragma unroll
    for (int t = 0; t < 8; ++t)
      breg[t] = ok ? *(const f16x8*)(Bp + t * 32 + hi * 8) : z;
  }

  // epilogue constants: 2 vector loads from pre-transposed table
  float4 fb1r = *(const float4*)(fbw + jl * 8);
  float4 fw2r = *(const float4*)(fbw + jl * 8 + 4);
  float bias2 = fbw[128];

  __syncthreads();

  #pragma unroll 1
  for (int ig = 0; ig < ITILE / IBLK; ++ig) {
    f32x4 acc[IBLK][4] = {};
    #pragma unroll
    for (int t = 0; t < 8; ++t) {
      f16x8 bv = breg[t];
      f16x8 af[IBLK];
      const f16x8 Zv{};
      #pragma unroll
      for (int ib = 0; ib < IBLK; ++ib) {
        f16x8 av = *(const f16x8*)(sA + (ig * IBLK + ib) * 256 + t * 32 + hi * 8);
        af[ib] = __builtin_elementwise_max(av + bv, Zv);  // pk_add + pk_max
      }
      int kbyte = t * 64 + hi * 16;
      #pragma unroll
      for (int nf = 0; nf < 4; ++nf) {
        int n = nf * 16 + jl;
        f16x8 wh = *(const f16x8*)(sWh + n * 512 + (kbyte ^ ((n & 7) << 4)));
        #pragma unroll
        for (int ib = 0; ib < IBLK; ++ib)
          acc[ib][nf] = mfma_f16(af[ib], wh, acc[ib][nf]);
      }
    }
    // epilogue: h1 = relu(acc + fb1); out = h1 . fW2 + fb2
    float fb1a[4] = {fb1r.x, fb1r.y, fb1r.z, fb1r.w};
    float fw2a[4] = {fw2r.x, fw2r.y, fw2r.z, fw2r.w};
    #pragma unroll
    for (int ib = 0; ib < IBLK; ++ib) {
      float part[4];
      #pragma unroll
      for (int r = 0; r < 4; ++r) {
        float ssum = 0.f;
        #pragma unroll
        for (int nf = 0; nf < 4; ++nf) {
          float h = acc[ib][nf][r] + fb1a[nf];
          h = fmaxf(h, 0.f);
          ssum += h * fw2a[nf];
        }
        part[r] = ssum;
      }
      #pragma unroll
      for (int off = 1; off < 16; off <<= 1) {
        #pragma unroll
        for (int r = 0; r < 4; ++r) part[r] += __shfl_xor(part[r], off, 64);
      }
      if (jl == 0) {
        int jo = j0 + w * 16 + hi * 4;
        if (jo < N1R) {
          float4 o = make_float4(part[0] + bias2, part[1] + bias2,
                                 part[2] + bias2, part[3] + bias2);
          *(float4*)(out + (size_t)(i0 + ig * IBLK + ib) * 800 + jo) = o;
        }
      }
    }
  }
}

// ---------------------------------------------------------------------------
extern "C" void kernel_launch(void* const* d_in, const int* in_sizes, int n_in,
                              void* d_out, int out_size, void* d_ws, size_t ws_size,
                              hipStream_t stream) {
  const float* Z1   = (const float*)d_in[0];
  const int*   nb1  = (const int*)d_in[1];
  const float* Z2   = (const float*)d_in[2];
  const int*   nb2  = (const int*)d_in[3];
  const float* Wr0  = (const float*)d_in[4];
  const float* Wnr0 = (const float*)d_in[5];
  const float* Wr1  = (const float*)d_in[6];
  const float* Wnr1 = (const float*)d_in[7];
  const float* fW0  = (const float*)d_in[8];
  const float* fb0  = (const float*)d_in[9];
  const float* fW1  = (const float*)d_in[10];
  const float* fb1  = (const float*)d_in[11];
  const float* fW2  = (const float*)d_in[12];
  const float* fb2  = (const float*)d_in[13];
  float* out = (float*)d_out;

  // workspace carve
  char* p = (char*)d_ws;
  auto alloc = [&](size_t bytes) {
    char* q = p;
    p += (bytes + 255) & ~(size_t)255;
    return q;
  };
  bf16_t* W0h   = (bf16_t*)alloc((size_t)512 * 1024 * 2);
  bf16_t* W0l   = (bf16_t*)alloc((size_t)512 * 1024 * 2);
  bf16_t* W1h   = (bf16_t*)alloc((size_t)256 * 256 * 2);
  bf16_t* W1l   = (bf16_t*)alloc((size_t)256 * 256 * 2);
  bf16_t* fAh   = (bf16_t*)alloc((size_t)256 * 128 * 2);
  bf16_t* fAl   = (bf16_t*)alloc((size_t)256 * 128 * 2);
  bf16_t* fBh   = (bf16_t*)alloc((size_t)256 * 128 * 2);
  bf16_t* fBl   = (bf16_t*)alloc((size_t)256 * 128 * 2);
  f16_t*  fW1th = (f16_t*)alloc((size_t)64 * 256 * 2);
  float*  fbw   = (float*)alloc(129 * 4);
  bf16_t* H0h   = (bf16_t*)alloc((size_t)NR * F0 * 2);
  bf16_t* H0l   = (bf16_t*)alloc((size_t)NR * F0 * 2);
  bf16_t* H1h   = (bf16_t*)alloc((size_t)NR * F1 * 2);
  bf16_t* H1l   = (bf16_t*)alloc((size_t)NR * F1 * 2);
  f16_t*  ABh   = (f16_t*)alloc((size_t)NR * 256 * 2);
  // split-K partial buffers (sized to fit; S chosen by available ws)
  size_t part1 = (size_t)NR * 512 * 4;
  size_t part2 = (size_t)NR * 256 * 4;
  size_t used = (size_t)(p - (char*)d_ws);
  int S = 1, S2 = 1;
  if (used + 4 * part1 + 4 * part2 + 2048 <= ws_size) { S = 4; S2 = 4; }
  else if (used + 2 * part1 + 2 * part2 + 2048 <= ws_size) { S = 2; S2 = 2; }
  float* RB0p = (float*)alloc(S * part1);
  float* RB1p = (float*)alloc(S2 * part2);
  (void)in_sizes; (void)n_in; (void)out_size;

  // 1. weight conversion + epilogue table
  conv_w<<<2625, 256, 0, stream>>>(Wr0, Wnr0, Wr1, Wnr1, fW0, fW1, fb1, fW2, fb2,
                                   W0h, W0l, W1h, W1l, fAh, fAl, fBh, fBl,
                                   fW1th, fbw);
  // 2. gemm1 (split-K S, A from f32 Z on the fly): RB0p[z] = Z @ [Wr0|Wnr0]
  gemm_z<<<dim3(8, 25, S), 256, 0, stream>>>(Z1, Z2, W0h, W0l, RB0p, 1024 / S);
  // 3. aggregate (sums S partials inline) -> H0 hi/lo
  agg_kernel<<<NR, 256, 0, stream>>>(RB0p, nb1, nb2, H0h, H0l, F0, S);
  // 4. gemm2 (split-K S2): RB1p[z] = H0 @ [Wr1|Wnr1]
  gemm_split<<<dim3(4, 25, S2), 256, 0, stream>>>(H0h, H0l, W1h, W1l, RB1p,
                                                  NR, 256, 256, 256 / S2);
  // 5. aggregate (sums S2 partials inline) -> H1 hi/lo
  agg_kernel<<<NR, 128, 0, stream>>>(RB1p, nb1, nb2, H1h, H1l, F1, S2);
  // 6. A' and B in one launch -> f16
  gemm_dual<<<dim3(4, 26), 256, 0, stream>>>(H1h, H1l, fAh, fAl, fBh, fBl, fb0, ABh);
  // 7. all-pairs fused MLP (fp16 datapath)
  pair_kernel<<<dim3(13, 50), 256, 0, stream>>>(ABh, fW1th, fbw, out);
}